// Round 1
// baseline (63.641 us; speedup 1.0000x reference)
//
#include <hip/hip_runtime.h>

// ReflexPolicy: B=8192, OBS=64, ACT=32, LAT=25, H=5, SUP_H=64
// Fused single kernel, fp32 throughout.
// grid = 512 blocks x 256 threads, BT=16 rows/block.

#define TOBS 64
#define TACT 32
#define TLAT 25
#define TH   5
#define TB   8192
#define BT   16     // batch rows per block
#define OCH  8      // obs indices per staged chunk
#define NCHUNK (TOBS / OCH)
#define LATP 29     // padded latent stride in staged A (odd -> conflict-free)
#define OSTR 68     // padded row stride for obs/h tiles

__device__ __forceinline__ float sigmoidf_(float x) {
    return 1.0f / (1.0f + __expf(-x));
}

__global__ __launch_bounds__(256, 2)
void reflex_fused(const float* __restrict__ obs,
                  const float* __restrict__ sw1, const float* __restrict__ sb1,
                  const float* __restrict__ sw2, const float* __restrict__ sb2,
                  const float* __restrict__ sw3, const float* __restrict__ sb3,
                  const float* __restrict__ rw1, const float* __restrict__ rb1,
                  const float* __restrict__ rw2, const float* __restrict__ rb2,
                  const float* __restrict__ am,  float* __restrict__ out)
{
    __shared__ __align__(16) float obs_s[BT * OSTR];
    __shared__ __align__(16) float h1_s[BT * OSTR];
    __shared__ __align__(16) float h2_s[BT * OSTR];
    __shared__ __align__(16) float lat_s[BT * 28];
    __shared__ __align__(16) float sb1_s[64];
    __shared__ __align__(16) float sb2_s[64];
    __shared__ __align__(16) float sb3_s[32];
    __shared__ __align__(16) union {
        struct { float w1[64 * 64]; float w2[64 * 64]; float w3[64 * 26]; } p1;
        struct { float At[OCH * TACT * LATP];
                 float w1[TH * OCH * TACT]; float b1[TH * OCH * TACT];
                 float w2[TH * OCH * TACT]; float b2[OCH * TACT]; } p2;
    } U;

    const int tid  = threadIdx.x;
    const int row0 = blockIdx.x * BT;

    // ---------------- Phase 1: stage obs tile + supervisor weights ----------------
    for (int i = tid; i < BT * TOBS; i += 256) {
        int r = i >> 6, k = i & 63;
        obs_s[r * OSTR + k] = obs[(row0 + r) * TOBS + k];
    }
    for (int i = tid; i < 64 * 64; i += 256) U.p1.w1[i] = sw1[i];
    for (int i = tid; i < 64 * 64; i += 256) U.p1.w2[i] = sw2[i];
    for (int i = tid; i < 64 * 25; i += 256) {
        int k = i / 25, j = i - k * 25;
        U.p1.w3[k * 26 + j] = sw3[i];
    }
    if (tid < 64) { sb1_s[tid] = sb1[tid]; sb2_s[tid] = sb2[tid]; }
    if (tid < 32) sb3_s[tid] = (tid < TLAT) ? sb3[tid] : 0.0f;
    __syncthreads();

    // Supervisor layer 1: h1 = relu(obs @ sw1 + sb1). 16 threads/row, 4 j each.
    {
        const int r = tid >> 4, q = tid & 15, j0 = q * 4;
        float a0 = sb1_s[j0], a1 = sb1_s[j0 + 1], a2 = sb1_s[j0 + 2], a3 = sb1_s[j0 + 3];
        #pragma unroll 8
        for (int k = 0; k < 64; ++k) {
            float x = obs_s[r * OSTR + k];
            const float4 w = *(const float4*)&U.p1.w1[k * 64 + j0];
            a0 = fmaf(x, w.x, a0); a1 = fmaf(x, w.y, a1);
            a2 = fmaf(x, w.z, a2); a3 = fmaf(x, w.w, a3);
        }
        float4 hv = make_float4(fmaxf(a0, 0.f), fmaxf(a1, 0.f), fmaxf(a2, 0.f), fmaxf(a3, 0.f));
        *(float4*)&h1_s[r * OSTR + j0] = hv;
    }
    __syncthreads();

    // Supervisor layer 2: h2 = relu(h1 @ sw2 + sb2)
    {
        const int r = tid >> 4, q = tid & 15, j0 = q * 4;
        float a0 = sb2_s[j0], a1 = sb2_s[j0 + 1], a2 = sb2_s[j0 + 2], a3 = sb2_s[j0 + 3];
        #pragma unroll 8
        for (int k = 0; k < 64; ++k) {
            float x = h1_s[r * OSTR + k];
            const float4 w = *(const float4*)&U.p1.w2[k * 64 + j0];
            a0 = fmaf(x, w.x, a0); a1 = fmaf(x, w.y, a1);
            a2 = fmaf(x, w.z, a2); a3 = fmaf(x, w.w, a3);
        }
        float4 hv = make_float4(fmaxf(a0, 0.f), fmaxf(a1, 0.f), fmaxf(a2, 0.f), fmaxf(a3, 0.f));
        *(float4*)&h2_s[r * OSTR + j0] = hv;
    }
    __syncthreads();

    // Supervisor layer 3: latent = sigmoid(h2 @ sw3 + sb3). 16 threads/row, 2 j each (j<25 masked).
    {
        const int r = tid >> 4, q = tid & 15, j = q * 2;
        float a0 = sb3_s[j & 31], a1 = sb3_s[(j + 1) & 31];
        #pragma unroll 8
        for (int k = 0; k < 64; ++k) {
            float x = h2_s[r * OSTR + k];
            // j can reach 30; reads stay inside the (larger) union allocation.
            a0 = fmaf(x, U.p1.w3[k * 26 + j], a0);
            a1 = fmaf(x, U.p1.w3[k * 26 + j + 1], a1);
        }
        if (j < TLAT)     lat_s[r * 28 + j]     = sigmoidf_(a0);
        if (j + 1 < TLAT) lat_s[r * 28 + j + 1] = sigmoidf_(a1);
    }
    __syncthreads();

    // ---------------- Phase 2: gating + reflex, half-wave per 2 rows ----------------
    const int lane = tid & 63;
    const int a    = lane & 31;
    const int hw   = tid >> 5;          // 0..7 half-wave id
    const int r0   = hw * 2, r1 = hw * 2 + 1;

    float latA[TLAT], latB[TLAT];
    #pragma unroll
    for (int l = 0; l < TLAT; ++l) {
        latA[l] = lat_s[r0 * 28 + l];
        latB[l] = lat_s[r1 * 28 + l];
    }
    float acc0 = 0.f, acc1 = 0.f;

    for (int c = 0; c < NCHUNK; ++c) {
        const int o0 = c * OCH;
        __syncthreads();   // previous chunk compute (or phase-1 reads) done

        // stage A chunk: At[(oc*32+a)*LATP + l] = am[l][o0+oc][a]
        {
            const int oc = tid >> 5, a_ = tid & 31;
            const int o  = o0 + oc;
            #pragma unroll
            for (int l = 0; l < TLAT; ++l)
                U.p2.At[tid * LATP + l] = am[(l * TOBS + o) * TACT + a_];
        }
        // stage reflex weights: [h][oc][a]
        for (int i = tid; i < TH * OCH * TACT; i += 256) {
            int h = i >> 8, j = i & 255;
            int o = o0 + (j >> 5), a_ = j & 31;
            int gi = (o * TACT + a_) * TH + h;
            U.p2.w1[i] = rw1[gi];
            U.p2.b1[i] = rb1[gi];
            U.p2.w2[i] = rw2[gi];
        }
        for (int i = tid; i < OCH * TACT; i += 256)
            U.p2.b2[i] = rb2[(o0 + (i >> 5)) * TACT + (i & 31)];
        __syncthreads();

        for (int oc = 0; oc < OCH; ++oc) {
            const int o  = o0 + oc;
            const int jb = oc * TACT + a;

            // logits for 2 rows
            float l0 = 0.f, l1 = 0.f;
            const int ab = jb * LATP;
            #pragma unroll
            for (int l = 0; l < TLAT; ++l) {
                float Av = U.p2.At[ab + l];
                l0 = fmaf(Av, latA[l], l0);
                l1 = fmaf(Av, latB[l], l1);
            }
            float e0 = __expf(l0), e1 = __expf(l1);

            // softmax denominator over the 32-lane half-wave
            float s0 = e0, s1 = e1;
            #pragma unroll
            for (int d = 16; d >= 1; d >>= 1) {
                s0 += __shfl_xor(s0, d);
                s1 += __shfl_xor(s1, d);
            }
            float p0 = e0 * __builtin_amdgcn_rcpf(s0);
            float p1 = e1 * __builtin_amdgcn_rcpf(s1);

            // reflex MLPs (1->5->1), shared weight reads across both rows
            float x0 = obs_s[r0 * OSTR + o], x1 = obs_s[r1 * OSTR + o];
            float ro0 = U.p2.b2[jb], ro1 = ro0;
            #pragma unroll
            for (int h = 0; h < TH; ++h) {
                float w1v = U.p2.w1[h * 256 + jb];
                float b1v = U.p2.b1[h * 256 + jb];
                float w2v = U.p2.w2[h * 256 + jb];
                float t0 = fmaxf(fmaf(x0, w1v, b1v), 0.f);
                float t1 = fmaxf(fmaf(x1, w1v, b1v), 0.f);
                ro0 = fmaf(t0, w2v, ro0);
                ro1 = fmaf(t1, w2v, ro1);
            }
            acc0 = fmaf(ro0, p0, acc0);
            acc1 = fmaf(ro1, p1, acc1);
        }
    }

    out[(row0 + r0) * TACT + a] = acc0;
    out[(row0 + r1) * TACT + a] = acc1;
}

extern "C" void kernel_launch(void* const* d_in, const int* in_sizes, int n_in,
                              void* d_out, int out_size, void* d_ws, size_t ws_size,
                              hipStream_t stream) {
    const float* obs = (const float*)d_in[0];
    const float* sw1 = (const float*)d_in[1];
    const float* sb1 = (const float*)d_in[2];
    const float* sw2 = (const float*)d_in[3];
    const float* sb2 = (const float*)d_in[4];
    const float* sw3 = (const float*)d_in[5];
    const float* sb3 = (const float*)d_in[6];
    const float* rw1 = (const float*)d_in[7];
    const float* rb1 = (const float*)d_in[8];
    const float* rw2 = (const float*)d_in[9];
    const float* rb2 = (const float*)d_in[10];
    const float* am  = (const float*)d_in[11];
    float* out = (float*)d_out;

    reflex_fused<<<TB / BT, 256, 0, stream>>>(obs, sw1, sb1, sw2, sb2, sw3, sb3,
                                              rw1, rb1, rw2, rb2, am, out);
}